// Round 1
// 261.864 us; speedup vs baseline: 1.0574x; 1.0574x over previous
//
#include <hip/hip_runtime.h>

typedef short s16x8 __attribute__((ext_vector_type(8)));
typedef unsigned short u16x8 __attribute__((ext_vector_type(8)));
typedef float f32x4 __attribute__((ext_vector_type(4)));
typedef unsigned short ushort;

// ---------------- problem constants ----------------
#define NTOK 1024
#define DHID 512

// head: W0 (20000) + cluster_weight (3) = 20003 rows, K=512
#define VH   20003
#define KH   512
#define NCH_H 80
#define TPC_H 16      // 80 chunks * 16 tiles * 16 = 20480 padded rows
#define VH_PAD 20480

// tail1: 20000 rows, K=128
#define V1   20000
#define K1   128
#define NCH_1 80
#define TPC_1 16      // 20480
#define V1_PAD 20480

// tail2: 160000 rows, K=32
#define V2   160000
#define K2   32
#define NCH_2 128
#define TPC_2 80      // 128*80*16 = 163840
#define V2_PAD 163840

// tail3: 67735 rows, K=8 padded to 32
#define V3   67735
#define K3   32
#define NCH_3 67
#define TPC_3 64      // 67*64*16 = 68608
#define V3_PAD 68608

#define PAD_BIAS (-1e30f)

// ---------------- ws layout (bytes) ----------------
#define OFF_HW   0UL
#define OFF_W1   (OFF_HW  + (unsigned long)VH_PAD*KH*2)
#define OFF_W2   (OFF_W1  + (unsigned long)V1_PAD*K1*2)
#define OFF_W3   (OFF_W2  + (unsigned long)V2_PAD*K2*2)
#define OFF_HID  (OFF_W3  + (unsigned long)V3_PAD*K3*2)
#define OFF_PT0  (OFF_HID + (unsigned long)NTOK*DHID*2)
#define OFF_PT1  (OFF_PT0 + (unsigned long)512*DHID*2)
#define OFF_PT2  (OFF_PT1 + (unsigned long)128*DHID*2)
#define OFF_PT3  (OFF_PT2 + (unsigned long)32*DHID*2)
#define OFF_H0   (OFF_PT3 + (unsigned long)32*DHID*2)
#define OFF_H1   (OFF_H0  + (unsigned long)NTOK*512*2)
#define OFF_H2   (OFF_H1  + (unsigned long)NTOK*128*2)
#define OFF_H3   (OFF_H2  + (unsigned long)NTOK*32*2)
#define OFF_HB   (OFF_H3  + (unsigned long)NTOK*32*2)
#define OFF_B1   (OFF_HB  + (unsigned long)VH_PAD*4)
#define OFF_B2   (OFF_B1  + (unsigned long)V1_PAD*4)
#define OFF_B3   (OFF_B2  + (unsigned long)V2_PAD*4)
#define OFF_SH   (OFF_B3  + (unsigned long)V3_PAD*4)
#define OFF_S1   (OFF_SH  + (unsigned long)NTOK*NCH_H*4)
#define OFF_S2   (OFF_S1  + (unsigned long)NTOK*NCH_1*4)
#define OFF_S3   (OFF_S2  + (unsigned long)NTOK*NCH_2*4)

// ---------------- helpers ----------------
__device__ __forceinline__ ushort f2bf(float f) {
    union { float f; unsigned u; } x; x.f = f;
    unsigned r = x.u + 0x7fffu + ((x.u >> 16) & 1u);
    return (ushort)(r >> 16);
}
__device__ __forceinline__ float bf2f(ushort h) {
    union { unsigned u; float f; } x; x.u = ((unsigned)h) << 16;
    return x.f;
}
__device__ __forceinline__ f32x4 mfma_bf16(s16x8 a, s16x8 b, f32x4 c) {
    return __builtin_amdgcn_mfma_f32_16x16x32_bf16(a, b, c, 0, 0, 0);
}
__device__ __forceinline__ void ld8(const float* p, float* v) {
    float4 a = *(const float4*)p, b = *(const float4*)(p + 4);
    v[0]=a.x; v[1]=a.y; v[2]=a.z; v[3]=a.w; v[4]=b.x; v[5]=b.y; v[6]=b.z; v[7]=b.w;
}

// async global->LDS, 16B per lane. LDS dest is wave-uniform base + lane*16.
__device__ __forceinline__ void gld_lds16(const ushort* g, ushort* l) {
    __builtin_amdgcn_global_load_lds(
        (const __attribute__((address_space(1))) unsigned int*)g,
        (__attribute__((address_space(3))) unsigned int*)l, 16, 0, 0);
}

// ---------------- prep: wave-per-512-element-block swizzle ----------------
#define WB_HW  20480L
#define WB_W1  5120L
#define WB_W2  10240L
#define WB_W3  4288L
#define WB_HID 1024L
#define WB_PT0 512L
#define WB_PT1 128L
#define WB_PT2 32L
#define WB_PT3 32L
#define WB_TOTAL (WB_HW+WB_W1+WB_W2+WB_W3+WB_HID+WB_PT0+WB_PT1+WB_PT2+WB_PT3)

__global__ __launch_bounds__(256) void prep_wswz(
    const float* __restrict__ hidden,
    const float* __restrict__ W0, const float* __restrict__ cw,
    const float* __restrict__ W1, const float* __restrict__ W2, const float* __restrict__ W3,
    const float* __restrict__ p0, const float* __restrict__ p1,
    const float* __restrict__ p2, const float* __restrict__ p3,
    ushort* __restrict__ hw, ushort* __restrict__ ow1,
    ushort* __restrict__ ow2, ushort* __restrict__ ow3,
    ushort* __restrict__ hid,
    ushort* __restrict__ pT0, ushort* __restrict__ pT1,
    ushort* __restrict__ pT2, ushort* __restrict__ pT3)
{
    int lane = threadIdx.x & 63;
    int r = lane & 15, quad = lane >> 4;
    long wb0 = (long)blockIdx.x * 4 + (threadIdx.x >> 6);
    long nw = (long)gridDim.x * 4;
    for (long wb = wb0; wb < WB_TOTAL; wb += nw) {
        long b = wb;
        float vals[8];
        #pragma unroll
        for (int j = 0; j < 8; ++j) vals[j] = 0.f;
        ushort* dst;
        if (b < WB_HW) {
            long tile = b >> 4, ks = b & 15;
            long v = tile * 16 + r, k = ks * 32 + quad * 8;
            if (v < 20000)      ld8(W0 + v * 512 + k, vals);
            else if (v < VH)    ld8(cw + (v - 20000) * 512 + k, vals);
            dst = hw + b * 512 + (long)lane * 8;
        } else if ((b -= WB_HW) < WB_W1) {
            long tile = b >> 2, ks = b & 3;
            long v = tile * 16 + r, k = ks * 32 + quad * 8;
            if (v < V1) ld8(W1 + v * 128 + k, vals);
            dst = ow1 + b * 512 + (long)lane * 8;
        } else if ((b -= WB_W1) < WB_W2) {
            long v = b * 16 + r;
            if (v < V2) ld8(W2 + v * 32 + quad * 8, vals);
            dst = ow2 + b * 512 + (long)lane * 8;
        } else if ((b -= WB_W2) < WB_W3) {
            long v = b * 16 + r;
            if (v < V3 && quad == 0) ld8(W3 + v * 8, vals);
            dst = ow3 + b * 512 + (long)lane * 8;
        } else if ((b -= WB_W3) < WB_HID) {
            long tile = b >> 4, ks = b & 15;
            long v = tile * 16 + r, k = ks * 32 + quad * 8;
            ld8(hidden + v * 512 + k, vals);
            dst = hid + b * 512 + (long)lane * 8;
        } else if ((b -= WB_HID) < WB_PT0) {
            long tile = b >> 4, ks = b & 15;
            long c = tile * 16 + r, k = ks * 32 + quad * 8;
            #pragma unroll
            for (int j = 0; j < 8; ++j) vals[j] = p0[(k + j) * 512 + c];
            dst = pT0 + b * 512 + (long)lane * 8;
        } else if ((b -= WB_PT0) < WB_PT1) {
            long tile = b >> 4, ks = b & 15;
            long c = tile * 16 + r, k = ks * 32 + quad * 8;
            #pragma unroll
            for (int j = 0; j < 8; ++j) vals[j] = p1[(k + j) * 128 + c];
            dst = pT1 + b * 512 + (long)lane * 8;
        } else if ((b -= WB_PT1) < WB_PT2) {
            long tile = b >> 4, ks = b & 15;
            long c = tile * 16 + r, k = ks * 32 + quad * 8;
            #pragma unroll
            for (int j = 0; j < 8; ++j) vals[j] = p2[(k + j) * 32 + c];
            dst = pT2 + b * 512 + (long)lane * 8;
        } else {
            b -= WB_PT2;
            long tile = b >> 4, ks = b & 15;
            long c = tile * 16 + r, k = ks * 32 + quad * 8;
            if (c < 8) {
                #pragma unroll
                for (int j = 0; j < 8; ++j) vals[j] = p3[(k + j) * 8 + c];
            }
            dst = pT3 + b * 512 + (long)lane * 8;
        }
        u16x8 o;
        #pragma unroll
        for (int j = 0; j < 8; ++j) o[j] = f2bf(vals[j]);
        *(u16x8*)dst = o;
    }
}

// ---------------- prep: padded biases ----------------
#define E_HB  ((long)VH_PAD)
#define E_B1  ((long)V1_PAD)
#define E_B2  ((long)V2_PAD)
#define E_B3  ((long)V3_PAD)
#define E_BIAS (E_HB+E_B1+E_B2+E_B3)

__global__ __launch_bounds__(256) void prep_bias(
    const float* __restrict__ b0, const float* __restrict__ b1,
    const float* __restrict__ b2, const float* __restrict__ b3,
    const float* __restrict__ cb,
    float* __restrict__ hbp, float* __restrict__ ob1,
    float* __restrict__ ob2, float* __restrict__ ob3)
{
    long stride = (long)gridDim.x * blockDim.x;
    for (long i = (long)blockIdx.x * blockDim.x + threadIdx.x; i < E_BIAS; i += stride) {
        long j = i;
        if (j < E_HB) {
            hbp[j] = (j < 20000) ? b0[j] : (j < VH) ? cb[j - 20000] : PAD_BIAS;
        } else if ((j -= E_HB) < E_B1) {
            ob1[j] = (j < V1) ? b1[j] : PAD_BIAS;
        } else if ((j -= E_B1) < E_B2) {
            ob2[j] = (j < V2) ? b2[j] : PAD_BIAS;
        } else { j -= E_B2;
            ob3[j] = (j < V3) ? b3[j] : PAD_BIAS;
        }
    }
}

// ---------------- gemm_h: H_i = hidden @ proj_i (all operands swizzled) ----------------
__global__ __launch_bounds__(256) void gemm_h(
    const ushort* __restrict__ A, const ushort* __restrict__ Bt,
    ushort* __restrict__ Hout, int dpad)
{
    int wave = threadIdx.x >> 6, lane = threadIdx.x & 63;
    int quad = lane >> 4, colid = lane & 15;
    int m_tile = blockIdx.x * 4 + wave;
    int c_tile = blockIdx.y;
    const ushort* Ab = A + ((long)m_tile * 16) * 512 + lane * 8;
    const ushort* Bb = Bt + ((long)c_tile * 16) * 512 + lane * 8;
    f32x4 acc = {0.f, 0.f, 0.f, 0.f};
    #pragma unroll
    for (int ks = 0; ks < 16; ++ks) {
        s16x8 a = *(const s16x8*)(Ab + ks * 512);
        s16x8 b = *(const s16x8*)(Bb + ks * 512);
        acc = mfma_bf16(a, b, acc);
    }
    int KBo = dpad >> 5;
    int col = c_tile * 16 + colid;
    int ks_o = col >> 5, q_o = (col >> 3) & 3, j_o = col & 7;
    #pragma unroll
    for (int r = 0; r < 4; ++r) {
        int rm = quad * 4 + r;
        Hout[((long)m_tile * KBo + ks_o) * 512 + (q_o * 16 + rm) * 8 + j_o] = f2bf(acc[r]);
    }
}

// ---------------- fused GEMM + exp-sum, LDS double-buffered pipeline ----------------
// Group = TG consecutive 512-elem blocks (TG KB of LDS). Tiles/group = TG/KB.
// 4 waves share the staged W; A fragments live in registers for the whole chunk.

template<int TG>
__device__ __forceinline__ void stage_grp(const ushort* __restrict__ gsrc_base,
                                          ushort* __restrict__ buf,
                                          int wave, int lane)
{
    constexpr int LPW = TG / 4;                    // blocks staged per wave
    const ushort* g = gsrc_base + ((long)wave * LPW) * 512 + lane * 8;
    ushort* l = buf + (wave * LPW) * 512;          // wave-uniform LDS base
    #pragma unroll
    for (int i = 0; i < LPW; ++i)
        gld_lds16(g + i * 512, l + i * 512);
}

template<int KB, int TG>
__device__ __forceinline__ void compute_grp(const ushort* __restrict__ buf,
                                            const s16x8 (&afrag)[KB],
                                            const float* __restrict__ bias,
                                            long tile0, int lane, int colid,
                                            float (&s_acc)[4])
{
    constexpr int TPG = TG / KB;
    f32x4 acc0[TPG], acc1[TPG];
    #pragma unroll
    for (int t = 0; t < TPG; ++t) {
        acc0[t] = (f32x4){0.f, 0.f, 0.f, 0.f};
        acc1[t] = (f32x4){0.f, 0.f, 0.f, 0.f};
    }
    #pragma unroll
    for (int b = 0; b < TG; ++b) {
        s16x8 bb = *(const s16x8*)(buf + b * 512 + lane * 8);
        int t = b / KB, ks = b % KB;               // compile-time after unroll
        if ((KB > 1) && (ks & 1))
            acc1[t] = mfma_bf16(afrag[ks], bb, acc1[t]);
        else
            acc0[t] = mfma_bf16(afrag[ks], bb, acc0[t]);
    }
    #pragma unroll
    for (int t = 0; t < TPG; ++t) {
        float bval = bias[(tile0 + t) * 16 + colid];
        #pragma unroll
        for (int r = 0; r < 4; ++r) {
            float v = acc0[t][r];
            if (KB > 1) v += acc1[t][r];
            s_acc[r] += __expf(v + bval);
        }
    }
}

template<int KB, int TG>
__global__ __launch_bounds__(256, 4) void fused_lse_lds(
    const ushort* __restrict__ A, const ushort* __restrict__ W,
    const float* __restrict__ bias, float* __restrict__ part_s,
    int tpc, int n_chunks)
{
    constexpr int TPG = TG / KB;
    __shared__ __align__(16) ushort lds0[TG * 512];
    __shared__ __align__(16) ushort lds1[TG * 512];

    int wave = threadIdx.x >> 6, lane = threadIdx.x & 63;
    int quad = lane >> 4, colid = lane & 15;
    int m_tile = blockIdx.x * 4 + wave;
    long t0 = (long)blockIdx.y * tpc;
    const ushort* Wc = W + t0 * KB * 512;

    // hoist A fragments for this wave's m_tile (reused across all groups)
    s16x8 afrag[KB];
    const ushort* Ab = A + ((long)m_tile * KB) * 512 + lane * 8;
    #pragma unroll
    for (int ks = 0; ks < KB; ++ks) afrag[ks] = *(const s16x8*)(Ab + ks * 512);

    const int ng = (tpc * KB) / TG;                // groups per chunk (even for all shapes)
    float s_acc[4] = {0.f, 0.f, 0.f, 0.f};

    stage_grp<TG>(Wc, lds0, wave, lane);
    asm volatile("s_waitcnt vmcnt(0)" ::: "memory");
    __syncthreads();

    for (int g = 0; g < ng; g += 2) {
        if (g + 1 < ng)
            stage_grp<TG>(Wc + ((long)(g + 1) * TG) * 512, lds1, wave, lane);
        compute_grp<KB, TG>(lds0, afrag, bias, t0 + (long)g * TPG, lane, colid, s_acc);
        asm volatile("s_waitcnt vmcnt(0)" ::: "memory");
        __syncthreads();

        if (g + 2 < ng)
            stage_grp<TG>(Wc + ((long)(g + 2) * TG) * 512, lds0, wave, lane);
        if (g + 1 < ng) {
            compute_grp<KB, TG>(lds1, afrag, bias, t0 + (long)(g + 1) * TPG, lane, colid, s_acc);
            asm volatile("s_waitcnt vmcnt(0)" ::: "memory");
            __syncthreads();
        }
    }

    #pragma unroll
    for (int r = 0; r < 4; ++r) {
        float v = s_acc[r];
        v += __shfl_xor(v, 1);
        v += __shfl_xor(v, 2);
        v += __shfl_xor(v, 4);
        v += __shfl_xor(v, 8);
        s_acc[r] = v;
    }
    if (colid == 0) {
        #pragma unroll
        for (int r = 0; r < 4; ++r) {
            int m = m_tile * 16 + quad * 4 + r;
            part_s[(long)m * n_chunks + blockIdx.y] = s_acc[r];
        }
    }
}

// ---------------- finalize ----------------
__device__ __forceinline__ float swz_dot(const ushort* __restrict__ H, int m,
                                         const ushort* __restrict__ Wm, long vrow,
                                         int K, int lane)
{
    float d = 0.f;
    if (lane * 8 < K) {
        int ks = lane >> 2, q = lane & 3;
        int KB = K >> 5;
        const ushort* hp = H + ((long)(m >> 4) * KB + ks) * 512 + (q * 16 + (m & 15)) * 8;
        const ushort* wp = Wm + ((vrow >> 4) * KB + ks) * 512 + (q * 16 + (int)(vrow & 15)) * 8;
        #pragma unroll
        for (int j = 0; j < 8; ++j) d += bf2f(hp[j]) * bf2f(wp[j]);
    }
    d += __shfl_xor(d, 1);  d += __shfl_xor(d, 2);  d += __shfl_xor(d, 4);
    d += __shfl_xor(d, 8);  d += __shfl_xor(d, 16); d += __shfl_xor(d, 32);
    return d;
}

__global__ __launch_bounds__(256) void finalize_kernel(
    const int* __restrict__ target,
    const ushort* __restrict__ H0, const ushort* __restrict__ hw,
    const float* __restrict__ hbp, const float* __restrict__ sH,
    const ushort* __restrict__ H1, const ushort* __restrict__ w1,
    const float* __restrict__ b1p, const float* __restrict__ s1,
    const ushort* __restrict__ H2, const ushort* __restrict__ w2,
    const float* __restrict__ b2p, const float* __restrict__ s2,
    const ushort* __restrict__ H3, const ushort* __restrict__ w3,
    const float* __restrict__ b3p, const float* __restrict__ s3,
    float* __restrict__ out)
{
    int wave = threadIdx.x >> 6, lane = threadIdx.x & 63;
    int m = blockIdx.x * 4 + wave;
    int t = target[m];
    int cid = (t >= 20000) + (t >= 40000) + (t >= 200000);

    float s = 0.f;
    for (int i = lane; i < NCH_H; i += 64) s += sH[(long)m * NCH_H + i];
    s += __shfl_xor(s, 1);  s += __shfl_xor(s, 2);  s += __shfl_xor(s, 4);
    s += __shfl_xor(s, 8);  s += __shfl_xor(s, 16); s += __shfl_xor(s, 32);
    float lse_h = __logf(s);

    int hc = (cid == 0) ? t : (20003 - cid);
    float d = swz_dot(H0, m, hw, hc, 512, lane);
    float nll = lse_h - (d + hbp[hc]);

    if (cid > 0) {
        const ushort *Hi, *Wi; const float *bi, *si; int K, nc, l;
        if (cid == 1)      { Hi = H1; Wi = w1; bi = b1p; si = s1; K = 128; nc = NCH_1; l = 20000; }
        else if (cid == 2) { Hi = H2; Wi = w2; bi = b2p; si = s2; K = 32;  nc = NCH_2; l = 40000; }
        else               { Hi = H3; Wi = w3; bi = b3p; si = s3; K = 32;  nc = NCH_3; l = 200000; }
        int rel = t - l;
        float ts = 0.f;
        for (int i = lane; i < nc; i += 64) ts += si[(long)m * nc + i];
        ts += __shfl_xor(ts, 1);  ts += __shfl_xor(ts, 2);  ts += __shfl_xor(ts, 4);
        ts += __shfl_xor(ts, 8);  ts += __shfl_xor(ts, 16); ts += __shfl_xor(ts, 32);
        float lse_t = __logf(ts);
        float dt = swz_dot(Hi, m, Wi, rel, K, lane);
        nll += lse_t - (dt + bi[rel]);
    }
    if (lane == 0) out[m] = nll;
}

// ---------------- host ----------------
extern "C" void kernel_launch(void* const* d_in, const int* in_sizes, int n_in,
                              void* d_out, int out_size, void* d_ws, size_t ws_size,
                              hipStream_t stream) {
    const float* hidden = (const float*)d_in[0];
    const int*   target = (const int*)d_in[1];
    const float* W0 = (const float*)d_in[2];
    const float* b0 = (const float*)d_in[3];
    const float* p0 = (const float*)d_in[4];
    const float* W1 = (const float*)d_in[5];
    const float* b1 = (const float*)d_in[6];
    const float* p1 = (const float*)d_in[7];
    const float* W2 = (const float*)d_in[8];
    const float* b2 = (const float*)d_in[9];
    const float* p2 = (const float*)d_in[10];
    const float* W3 = (const float*)d_in[11];
    const float* b3 = (const float*)d_in[12];
    const float* p3 = (const float*)d_in[13];
    const float* cw = (const float*)d_in[14];
    const float* cb = (const float*)d_in[15];

    char* ws = (char*)d_ws;
    ushort* hw  = (ushort*)(ws + OFF_HW);
    ushort* ow1 = (ushort*)(ws + OFF_W1);
    ushort* ow2 = (ushort*)(ws + OFF_W2);
    ushort* ow3 = (ushort*)(ws + OFF_W3);
    ushort* hid = (ushort*)(ws + OFF_HID);
    ushort* pT0 = (ushort*)(ws + OFF_PT0);
    ushort* pT1 = (ushort*)(ws + OFF_PT1);
    ushort* pT2 = (ushort*)(ws + OFF_PT2);
    ushort* pT3 = (ushort*)(ws + OFF_PT3);
    ushort* H0  = (ushort*)(ws + OFF_H0);
    ushort* H1  = (ushort*)(ws + OFF_H1);
    ushort* H2  = (ushort*)(ws + OFF_H2);
    ushort* H3  = (ushort*)(ws + OFF_H3);
    float* hbp = (float*)(ws + OFF_HB);
    float* b1p = (float*)(ws + OFF_B1);
    float* b2p = (float*)(ws + OFF_B2);
    float* b3p = (float*)(ws + OFF_B3);
    float* sH  = (float*)(ws + OFF_SH);
    float* s1  = (float*)(ws + OFF_S1);
    float* s2  = (float*)(ws + OFF_S2);
    float* s3  = (float*)(ws + OFF_S3);

    prep_wswz<<<10464, 256, 0, stream>>>(hidden, W0, cw, W1, W2, W3,
                                         p0, p1, p2, p3,
                                         hw, ow1, ow2, ow3, hid, pT0, pT1, pT2, pT3);
    prep_bias<<<1072, 256, 0, stream>>>(b0, b1, b2, b3, cb, hbp, b1p, b2p, b3p);

    gemm_h<<<dim3(NTOK / 64, 512 / 16), 256, 0, stream>>>(hid, pT0, H0, 512);
    gemm_h<<<dim3(NTOK / 64, 128 / 16), 256, 0, stream>>>(hid, pT1, H1, 128);
    gemm_h<<<dim3(NTOK / 64, 32 / 16),  256, 0, stream>>>(hid, pT2, H2, 32);
    gemm_h<<<dim3(NTOK / 64, 32 / 16),  256, 0, stream>>>(hid, pT3, H3, 32);

    // head: KB=16 (K=512), group = 1 tile (16 blocks, 16KB/buf)
    fused_lse_lds<16, 16><<<dim3(NTOK / 64, NCH_H), 256, 0, stream>>>(H0, hw,  hbp, sH, TPC_H, NCH_H);
    // tail1: KB=4 (K=128), group = 2 tiles (8 blocks, 8KB/buf)
    fused_lse_lds<4, 8><<<dim3(NTOK / 64, NCH_1), 256, 0, stream>>>(H1, ow1, b1p, s1, TPC_1, NCH_1);
    // tail2/3: KB=1 (K=32), group = 8 tiles
    fused_lse_lds<1, 8><<<dim3(NTOK / 64, NCH_2), 256, 0, stream>>>(H2, ow2, b2p, s2, TPC_2, NCH_2);
    fused_lse_lds<1, 8><<<dim3(NTOK / 64, NCH_3), 256, 0, stream>>>(H3, ow3, b3p, s3, TPC_3, NCH_3);

    finalize_kernel<<<NTOK / 4, 256, 0, stream>>>(target,
        H0, hw, hbp, sH, H1, ow1, b1p, s1, H2, ow2, b2p, s2, H3, ow3, b3p, s3,
        (float*)d_out);
}

// Round 2
// 253.998 us; speedup vs baseline: 1.0901x; 1.0310x over previous
//
#include <hip/hip_runtime.h>

typedef short s16x8 __attribute__((ext_vector_type(8)));
typedef unsigned short u16x8 __attribute__((ext_vector_type(8)));
typedef float f32x4 __attribute__((ext_vector_type(4)));
typedef unsigned short ushort;

// ---------------- problem constants ----------------
#define NTOK 1024
#define DHID 512

#define VH   20003
#define KH   512
#define NCH_H 80
#define TPC_H 16
#define VH_PAD 20480

#define V1   20000
#define K1   128
#define NCH_1 80
#define TPC_1 16
#define V1_PAD 20480

#define V2   160000
#define K2   32
#define NCH_2 128
#define TPC_2 80
#define V2_PAD 163840

#define V3   67735
#define K3   32
#define NCH_3 67
#define TPC_3 64
#define V3_PAD 68608

#define PAD_BIAS (-1e30f)

// ---------------- ws layout (bytes) ----------------
#define OFF_HW   0UL
#define OFF_W1   (OFF_HW  + (unsigned long)VH_PAD*KH*2)
#define OFF_W2   (OFF_W1  + (unsigned long)V1_PAD*K1*2)
#define OFF_W3   (OFF_W2  + (unsigned long)V2_PAD*K2*2)
#define OFF_HID  (OFF_W3  + (unsigned long)V3_PAD*K3*2)
#define OFF_PT0  (OFF_HID + (unsigned long)NTOK*DHID*2)
#define OFF_PT1  (OFF_PT0 + (unsigned long)512*DHID*2)
#define OFF_PT2  (OFF_PT1 + (unsigned long)128*DHID*2)
#define OFF_PT3  (OFF_PT2 + (unsigned long)32*DHID*2)
#define OFF_H0   (OFF_PT3 + (unsigned long)32*DHID*2)
#define OFF_H1   (OFF_H0  + (unsigned long)NTOK*512*2)
#define OFF_H2   (OFF_H1  + (unsigned long)NTOK*128*2)
#define OFF_H3   (OFF_H2  + (unsigned long)NTOK*32*2)
#define OFF_HB   (OFF_H3  + (unsigned long)NTOK*32*2)
#define OFF_B1   (OFF_HB  + (unsigned long)VH_PAD*4)
#define OFF_B2   (OFF_B1  + (unsigned long)V1_PAD*4)
#define OFF_B3   (OFF_B2  + (unsigned long)V2_PAD*4)
#define OFF_SH   (OFF_B3  + (unsigned long)V3_PAD*4)
#define OFF_S1   (OFF_SH  + (unsigned long)NTOK*NCH_H*4)
#define OFF_S2   (OFF_S1  + (unsigned long)NTOK*NCH_1*4)
#define OFF_S3   (OFF_S2  + (unsigned long)NTOK*NCH_2*4)

// ---------------- helpers ----------------
__device__ __forceinline__ ushort f2bf(float f) {
    union { float f; unsigned u; } x; x.f = f;
    unsigned r = x.u + 0x7fffu + ((x.u >> 16) & 1u);
    return (ushort)(r >> 16);
}
__device__ __forceinline__ float bf2f(ushort h) {
    union { unsigned u; float f; } x; x.u = ((unsigned)h) << 16;
    return x.f;
}
__device__ __forceinline__ f32x4 mfma_bf16(s16x8 a, s16x8 b, f32x4 c) {
    return __builtin_amdgcn_mfma_f32_16x16x32_bf16(a, b, c, 0, 0, 0);
}
__device__ __forceinline__ void ld8(const float* p, float* v) {
    float4 a = *(const float4*)p, b = *(const float4*)(p + 4);
    v[0]=a.x; v[1]=a.y; v[2]=a.z; v[3]=a.w; v[4]=b.x; v[5]=b.y; v[6]=b.z; v[7]=b.w;
}
__device__ __forceinline__ void gld_lds16(const ushort* g, ushort* l) {
    __builtin_amdgcn_global_load_lds(
        (const __attribute__((address_space(1))) unsigned int*)g,
        (__attribute__((address_space(3))) unsigned int*)l, 16, 0, 0);
}

// ---------------- prep: wave-per-512-element-block swizzle ----------------
#define WB_HW  20480L
#define WB_W1  5120L
#define WB_W2  10240L
#define WB_W3  4288L
#define WB_HID 1024L
#define WB_PT0 512L
#define WB_PT1 128L
#define WB_PT2 32L
#define WB_PT3 32L
#define WB_TOTAL (WB_HW+WB_W1+WB_W2+WB_W3+WB_HID+WB_PT0+WB_PT1+WB_PT2+WB_PT3)

__global__ __launch_bounds__(256) void prep_wswz(
    const float* __restrict__ hidden,
    const float* __restrict__ W0, const float* __restrict__ cw,
    const float* __restrict__ W1, const float* __restrict__ W2, const float* __restrict__ W3,
    const float* __restrict__ p0, const float* __restrict__ p1,
    const float* __restrict__ p2, const float* __restrict__ p3,
    ushort* __restrict__ hw, ushort* __restrict__ ow1,
    ushort* __restrict__ ow2, ushort* __restrict__ ow3,
    ushort* __restrict__ hid,
    ushort* __restrict__ pT0, ushort* __restrict__ pT1,
    ushort* __restrict__ pT2, ushort* __restrict__ pT3)
{
    int lane = threadIdx.x & 63;
    int r = lane & 15, quad = lane >> 4;
    long wb0 = (long)blockIdx.x * 4 + (threadIdx.x >> 6);
    long nw = (long)gridDim.x * 4;
    for (long wb = wb0; wb < WB_TOTAL; wb += nw) {
        long b = wb;
        float vals[8];
        #pragma unroll
        for (int j = 0; j < 8; ++j) vals[j] = 0.f;
        ushort* dst;
        if (b < WB_HW) {
            long tile = b >> 4, ks = b & 15;
            long v = tile * 16 + r, k = ks * 32 + quad * 8;
            if (v < 20000)      ld8(W0 + v * 512 + k, vals);
            else if (v < VH)    ld8(cw + (v - 20000) * 512 + k, vals);
            dst = hw + b * 512 + (long)lane * 8;
        } else if ((b -= WB_HW) < WB_W1) {
            long tile = b >> 2, ks = b & 3;
            long v = tile * 16 + r, k = ks * 32 + quad * 8;
            if (v < V1) ld8(W1 + v * 128 + k, vals);
            dst = ow1 + b * 512 + (long)lane * 8;
        } else if ((b -= WB_W1) < WB_W2) {
            long v = b * 16 + r;
            if (v < V2) ld8(W2 + v * 32 + quad * 8, vals);
            dst = ow2 + b * 512 + (long)lane * 8;
        } else if ((b -= WB_W2) < WB_W3) {
            long v = b * 16 + r;
            if (v < V3 && quad == 0) ld8(W3 + v * 8, vals);
            dst = ow3 + b * 512 + (long)lane * 8;
        } else if ((b -= WB_W3) < WB_HID) {
            long tile = b >> 4, ks = b & 15;
            long v = tile * 16 + r, k = ks * 32 + quad * 8;
            ld8(hidden + v * 512 + k, vals);
            dst = hid + b * 512 + (long)lane * 8;
        } else if ((b -= WB_HID) < WB_PT0) {
            long tile = b >> 4, ks = b & 15;
            long c = tile * 16 + r, k = ks * 32 + quad * 8;
            #pragma unroll
            for (int j = 0; j < 8; ++j) vals[j] = p0[(k + j) * 512 + c];
            dst = pT0 + b * 512 + (long)lane * 8;
        } else if ((b -= WB_PT0) < WB_PT1) {
            long tile = b >> 4, ks = b & 15;
            long c = tile * 16 + r, k = ks * 32 + quad * 8;
            #pragma unroll
            for (int j = 0; j < 8; ++j) vals[j] = p1[(k + j) * 128 + c];
            dst = pT1 + b * 512 + (long)lane * 8;
        } else if ((b -= WB_PT1) < WB_PT2) {
            long tile = b >> 4, ks = b & 15;
            long c = tile * 16 + r, k = ks * 32 + quad * 8;
            #pragma unroll
            for (int j = 0; j < 8; ++j) vals[j] = p2[(k + j) * 32 + c];
            dst = pT2 + b * 512 + (long)lane * 8;
        } else {
            b -= WB_PT2;
            long tile = b >> 4, ks = b & 15;
            long c = tile * 16 + r, k = ks * 32 + quad * 8;
            if (c < 8) {
                #pragma unroll
                for (int j = 0; j < 8; ++j) vals[j] = p3[(k + j) * 8 + c];
            }
            dst = pT3 + b * 512 + (long)lane * 8;
        }
        u16x8 o;
        #pragma unroll
        for (int j = 0; j < 8; ++j) o[j] = f2bf(vals[j]);
        *(u16x8*)dst = o;
    }
}

// ---------------- prep: padded biases ----------------
#define E_HB  ((long)VH_PAD)
#define E_B1  ((long)V1_PAD)
#define E_B2  ((long)V2_PAD)
#define E_B3  ((long)V3_PAD)
#define E_BIAS (E_HB+E_B1+E_B2+E_B3)

__global__ __launch_bounds__(256) void prep_bias(
    const float* __restrict__ b0, const float* __restrict__ b1,
    const float* __restrict__ b2, const float* __restrict__ b3,
    const float* __restrict__ cb,
    float* __restrict__ hbp, float* __restrict__ ob1,
    float* __restrict__ ob2, float* __restrict__ ob3)
{
    long stride = (long)gridDim.x * blockDim.x;
    for (long i = (long)blockIdx.x * blockDim.x + threadIdx.x; i < E_BIAS; i += stride) {
        long j = i;
        if (j < E_HB) {
            hbp[j] = (j < 20000) ? b0[j] : (j < VH) ? cb[j - 20000] : PAD_BIAS;
        } else if ((j -= E_HB) < E_B1) {
            ob1[j] = (j < V1) ? b1[j] : PAD_BIAS;
        } else if ((j -= E_B1) < E_B2) {
            ob2[j] = (j < V2) ? b2[j] : PAD_BIAS;
        } else { j -= E_B2;
            ob3[j] = (j < V3) ? b3[j] : PAD_BIAS;
        }
    }
}

// ---------------- gemm_h body + merged launch ----------------
__device__ __forceinline__ void gemm_body(
    const ushort* __restrict__ A, const ushort* __restrict__ Bt,
    ushort* __restrict__ Hout, int dpad, int c_tile)
{
    int wave = threadIdx.x >> 6, lane = threadIdx.x & 63;
    int quad = lane >> 4, colid = lane & 15;
    int m_tile = blockIdx.x * 4 + wave;
    const ushort* Ab = A + ((long)m_tile * 16) * 512 + lane * 8;
    const ushort* Bb = Bt + ((long)c_tile * 16) * 512 + lane * 8;
    f32x4 acc = {0.f, 0.f, 0.f, 0.f};
    #pragma unroll
    for (int ks = 0; ks < 16; ++ks) {
        s16x8 a = *(const s16x8*)(Ab + ks * 512);
        s16x8 b = *(const s16x8*)(Bb + ks * 512);
        acc = mfma_bf16(a, b, acc);
    }
    int KBo = dpad >> 5;
    int col = c_tile * 16 + colid;
    int ks_o = col >> 5, q_o = (col >> 3) & 3, j_o = col & 7;
    #pragma unroll
    for (int r = 0; r < 4; ++r) {
        int rm = quad * 4 + r;
        Hout[((long)m_tile * KBo + ks_o) * 512 + (q_o * 16 + rm) * 8 + j_o] = f2bf(acc[r]);
    }
}

__global__ __launch_bounds__(256) void gemm_all(
    const ushort* __restrict__ hid,
    const ushort* __restrict__ pT0, const ushort* __restrict__ pT1,
    const ushort* __restrict__ pT2, const ushort* __restrict__ pT3,
    ushort* __restrict__ H0, ushort* __restrict__ H1,
    ushort* __restrict__ H2, ushort* __restrict__ H3)
{
    int y = blockIdx.y;
    if (y < 32)      gemm_body(hid, pT0, H0, 512, y);
    else if (y < 40) gemm_body(hid, pT1, H1, 128, y - 32);
    else if (y < 42) gemm_body(hid, pT2, H2, 32,  y - 40);
    else             gemm_body(hid, pT3, H3, 32,  y - 42);
}

// ---------------- fused GEMM + exp-sum: merged, 3-buffer 2-ahead pipeline ----------------
// Group = 16 blocks of 512 bf16 (16 KB). Per wave: 4 global_load_lds per stage.
// vmcnt counting is exact: the only VMEM in the main loop are stage loads.

__device__ __forceinline__ void stage_grp16(const ushort* __restrict__ g,
                                            ushort* __restrict__ l,
                                            int wave, int lane)
{
    const ushort* gp = g + ((long)wave * 4) * 512 + lane * 8;
    ushort* lp = l + wave * 4 * 512;
    #pragma unroll
    for (int i = 0; i < 4; ++i) gld_lds16(gp + i * 512, lp + i * 512);
}

template<int KB>
__device__ __forceinline__ void compute_grp16(const ushort* __restrict__ buf,
                                              const s16x8 (&afrag)[KB],
                                              const float* __restrict__ ldsB,
                                              int tb0, int lane, int colid,
                                              float (&s_acc)[4])
{
    constexpr int TPG = 16 / KB;
    f32x4 acc0[TPG], acc1[TPG];
    #pragma unroll
    for (int t = 0; t < TPG; ++t) {
        acc0[t] = (f32x4){0.f, 0.f, 0.f, 0.f};
        acc1[t] = (f32x4){0.f, 0.f, 0.f, 0.f};
    }
    #pragma unroll
    for (int b = 0; b < 16; ++b) {
        s16x8 bb = *(const s16x8*)(buf + b * 512 + lane * 8);
        int t = b / KB, ks = b % KB;              // compile-time after unroll
        if ((KB > 1) && (ks & 1))
            acc1[t] = mfma_bf16(afrag[ks], bb, acc1[t]);
        else
            acc0[t] = mfma_bf16(afrag[ks], bb, acc0[t]);
    }
    #pragma unroll
    for (int t = 0; t < TPG; ++t) {
        float bval = ldsB[(tb0 + t) * 16 + colid];
        #pragma unroll
        for (int r = 0; r < 4; ++r) {
            float v = acc0[t][r];
            if (KB > 1) v += acc1[t][r];
            s_acc[r] += __expf(v + bval);
        }
    }
}

template<int KB>
__device__ __forceinline__ void fused_path(const ushort* __restrict__ A,
                                           const ushort* __restrict__ W,
                                           const float* __restrict__ bias,
                                           float* __restrict__ part_s,
                                           int tpc, int n_chunks, int chunk, int mblk,
                                           ushort* __restrict__ ldsW,
                                           float* __restrict__ ldsB)
{
    constexpr int TPG = 16 / KB;
    int wave = threadIdx.x >> 6, lane = threadIdx.x & 63;
    int quad = lane >> 4, colid = lane & 15;
    int m_tile = mblk * 4 + wave;
    long t0 = (long)chunk * tpc;
    const ushort* Wc = W + t0 * KB * 512;
    int ng = (tpc * KB) >> 4;

    // A fragments (pinned in VGPRs below)
    s16x8 afrag[KB];
    const ushort* Ab = A + ((long)m_tile * KB) * 512 + lane * 8;
    #pragma unroll
    for (int ks = 0; ks < KB; ++ks) afrag[ks] = *(const s16x8*)(Ab + ks * 512);

    // bias -> LDS (keeps main loop free of stray VMEM)
    int nb = tpc * 16;
    for (int i = threadIdx.x; i < nb; i += 256) ldsB[i] = bias[t0 * 16 + i];
    __syncthreads();   // full drain once: afrag + bias loads complete
    #pragma unroll
    for (int ks = 0; ks < KB; ++ks) asm volatile("" : "+v"(afrag[ks]));

    float s_acc[4] = {0.f, 0.f, 0.f, 0.f};

    stage_grp16(Wc, ldsW, wave, lane);
    stage_grp16(Wc + 16 * 512, ldsW + 16 * 512, wave, lane);

    for (int g = 0; g < ng - 1; ++g) {
        asm volatile("s_waitcnt vmcnt(4)" ::: "memory");   // stage g landed (per-wave)
        __builtin_amdgcn_s_barrier();                      // all waves' stage g landed
        asm volatile("" ::: "memory");
        if (g + 2 < ng)
            stage_grp16(Wc + (long)(g + 2) * 16 * 512,
                        ldsW + ((g + 2) % 3) * (16 * 512), wave, lane);
        compute_grp16<KB>(ldsW + (g % 3) * (16 * 512), afrag, ldsB,
                          g * TPG, lane, colid, s_acc);
        asm volatile("s_waitcnt lgkmcnt(0)" ::: "memory"); // ds_reads done before next barrier
    }
    asm volatile("s_waitcnt vmcnt(0)" ::: "memory");
    __builtin_amdgcn_s_barrier();
    asm volatile("" ::: "memory");
    compute_grp16<KB>(ldsW + ((ng - 1) % 3) * (16 * 512), afrag, ldsB,
                      (ng - 1) * TPG, lane, colid, s_acc);

    #pragma unroll
    for (int r = 0; r < 4; ++r) {
        float v = s_acc[r];
        v += __shfl_xor(v, 1);
        v += __shfl_xor(v, 2);
        v += __shfl_xor(v, 4);
        v += __shfl_xor(v, 8);
        s_acc[r] = v;
    }
    if (colid == 0) {
        #pragma unroll
        for (int r = 0; r < 4; ++r) {
            int m = m_tile * 16 + quad * 4 + r;
            part_s[(long)m * n_chunks + chunk] = s_acc[r];
        }
    }
}

// grid: 5760 blocks; id -> (xcd k, chunk c, mblk) with all 16 m-blocks of a
// chunk on one XCD and chunk types stride-8 interleaved across XCDs.
__global__ __launch_bounds__(256, 3) void fused_all(
    const ushort* __restrict__ H0, const ushort* __restrict__ hw,
    const float* __restrict__ hbp, float* __restrict__ sH,
    const ushort* __restrict__ H1, const ushort* __restrict__ w1,
    const float* __restrict__ b1p, float* __restrict__ s1,
    const ushort* __restrict__ H2, const ushort* __restrict__ w2,
    const float* __restrict__ b2p, float* __restrict__ s2,
    const ushort* __restrict__ H3, const ushort* __restrict__ w3,
    const float* __restrict__ b3p, float* __restrict__ s3)
{
    __shared__ __align__(16) ushort ldsW[3 * 16 * 512];
    __shared__ float ldsB[1280];
    int id = blockIdx.x;
    int k = id & 7, s = id >> 3;
    int c = (s >> 4) * 8 + k;
    int mblk = s & 15;
    if (c >= 355) return;
    if (c < 80)       fused_path<16>(H0, hw, hbp, sH, TPC_H, NCH_H, c,       mblk, ldsW, ldsB);
    else if (c < 160) fused_path<4>(H1, w1, b1p, s1, TPC_1, NCH_1, c - 80,  mblk, ldsW, ldsB);
    else if (c < 288) fused_path<1>(H2, w2, b2p, s2, TPC_2, NCH_2, c - 160, mblk, ldsW, ldsB);
    else              fused_path<1>(H3, w3, b3p, s3, TPC_3, NCH_3, c - 288, mblk, ldsW, ldsB);
}

// ---------------- finalize ----------------
__device__ __forceinline__ float swz_dot(const ushort* __restrict__ H, int m,
                                         const ushort* __restrict__ Wm, long vrow,
                                         int K, int lane)
{
    float d = 0.f;
    if (lane * 8 < K) {
        int ks = lane >> 2, q = lane & 3;
        int KB = K >> 5;
        const ushort* hp = H + ((long)(m >> 4) * KB + ks) * 512 + (q * 16 + (m & 15)) * 8;
        const ushort* wp = Wm + ((vrow >> 4) * KB + ks) * 512 + (q * 16 + (int)(vrow & 15)) * 8;
        #pragma unroll
        for (int j = 0; j < 8; ++j) d += bf2f(hp[j]) * bf2f(wp[j]);
    }
    d += __shfl_xor(d, 1);  d += __shfl_xor(d, 2);  d += __shfl_xor(d, 4);
    d += __shfl_xor(d, 8);  d += __shfl_xor(d, 16); d += __shfl_xor(d, 32);
    return d;
}

__global__ __launch_bounds__(256) void finalize_kernel(
    const int* __restrict__ target,
    const ushort* __restrict__ H0, const ushort* __restrict__ hw,
    const float* __restrict__ hbp, const float* __restrict__ sH,
    const ushort* __restrict__ H1, const ushort* __restrict__ w1,
    const float* __restrict__ b1p, const float* __restrict__ s1,
    const ushort* __restrict__ H2, const ushort* __restrict__ w2,
    const float* __restrict__ b2p, const float* __restrict__ s2,
    const ushort* __restrict__ H3, const ushort* __restrict__ w3,
    const float* __restrict__ b3p, const float* __restrict__ s3,
    float* __restrict__ out)
{
    int wave = threadIdx.x >> 6, lane = threadIdx.x & 63;
    int m = blockIdx.x * 4 + wave;
    int t = target[m];
    int cid = (t >= 20000) + (t >= 40000) + (t >= 200000);

    float s = 0.f;
    for (int i = lane; i < NCH_H; i += 64) s += sH[(long)m * NCH_H + i];
    s += __shfl_xor(s, 1);  s += __shfl_xor(s, 2);  s += __shfl_xor(s, 4);
    s += __shfl_xor(s, 8);  s += __shfl_xor(s, 16); s += __shfl_xor(s, 32);
    float lse_h = __logf(s);

    int hc = (cid == 0) ? t : (20003 - cid);
    float d = swz_dot(H0, m, hw, hc, 512, lane);
    float nll = lse_h - (d + hbp[hc]);

    if (cid > 0) {
        const ushort *Hi, *Wi; const float *bi, *si; int K, nc, l;
        if (cid == 1)      { Hi = H1; Wi = w1; bi = b1p; si = s1; K = 128; nc = NCH_1; l = 20000; }
        else if (cid == 2) { Hi = H2; Wi = w2; bi = b2p; si = s2; K = 32;  nc = NCH_2; l = 40000; }
        else               { Hi = H3; Wi = w3; bi = b3p; si = s3; K = 32;  nc = NCH_3; l = 200000; }
        int rel = t - l;
        float ts = 0.f;
        for (int i = lane; i < nc; i += 64) ts += si[(long)m * nc + i];
        ts += __shfl_xor(ts, 1);  ts += __shfl_xor(ts, 2);  ts += __shfl_xor(ts, 4);
        ts += __shfl_xor(ts, 8);  ts += __shfl_xor(ts, 16); ts += __shfl_xor(ts, 32);
        float lse_t = __logf(ts);
        float dt = swz_dot(Hi, m, Wi, rel, K, lane);
        nll += lse_t - (dt + bi[rel]);
    }
    if (lane == 0) out[m] = nll;
}

// ---------------- host ----------------
extern "C" void kernel_launch(void* const* d_in, const int* in_sizes, int n_in,
                              void* d_out, int out_size, void* d_ws, size_t ws_size,
                              hipStream_t stream) {
    const float* hidden = (const float*)d_in[0];
    const int*   target = (const int*)d_in[1];
    const float* W0 = (const float*)d_in[2];
    const float* b0 = (const float*)d_in[3];
    const float* p0 = (const float*)d_in[4];
    const float* W1 = (const float*)d_in[5];
    const float* b1 = (const float*)d_in[6];
    const float* p1 = (const float*)d_in[7];
    const float* W2 = (const float*)d_in[8];
    const float* b2 = (const float*)d_in[9];
    const float* p2 = (const float*)d_in[10];
    const float* W3 = (const float*)d_in[11];
    const float* b3 = (const float*)d_in[12];
    const float* p3 = (const float*)d_in[13];
    const float* cw = (const float*)d_in[14];
    const float* cb = (const float*)d_in[15];

    char* ws = (char*)d_ws;
    ushort* hw  = (ushort*)(ws + OFF_HW);
    ushort* ow1 = (ushort*)(ws + OFF_W1);
    ushort* ow2 = (ushort*)(ws + OFF_W2);
    ushort* ow3 = (ushort*)(ws + OFF_W3);
    ushort* hid = (ushort*)(ws + OFF_HID);
    ushort* pT0 = (ushort*)(ws + OFF_PT0);
    ushort* pT1 = (ushort*)(ws + OFF_PT1);
    ushort* pT2 = (ushort*)(ws + OFF_PT2);
    ushort* pT3 = (ushort*)(ws + OFF_PT3);
    ushort* H0  = (ushort*)(ws + OFF_H0);
    ushort* H1  = (ushort*)(ws + OFF_H1);
    ushort* H2  = (ushort*)(ws + OFF_H2);
    ushort* H3  = (ushort*)(ws + OFF_H3);
    float* hbp = (float*)(ws + OFF_HB);
    float* b1p = (float*)(ws + OFF_B1);
    float* b2p = (float*)(ws + OFF_B2);
    float* b3p = (float*)(ws + OFF_B3);
    float* sH  = (float*)(ws + OFF_SH);
    float* s1  = (float*)(ws + OFF_S1);
    float* s2  = (float*)(ws + OFF_S2);
    float* s3  = (float*)(ws + OFF_S3);

    prep_wswz<<<10464, 256, 0, stream>>>(hidden, W0, cw, W1, W2, W3,
                                         p0, p1, p2, p3,
                                         hw, ow1, ow2, ow3, hid, pT0, pT1, pT2, pT3);
    prep_bias<<<1072, 256, 0, stream>>>(b0, b1, b2, b3, cb, hbp, b1p, b2p, b3p);

    gemm_all<<<dim3(NTOK / 64, 44), 256, 0, stream>>>(hid, pT0, pT1, pT2, pT3,
                                                      H0, H1, H2, H3);

    fused_all<<<5760, 256, 0, stream>>>(H0, hw, hbp, sH,
                                        H1, ow1, b1p, s1,
                                        H2, ow2, b2p, s2,
                                        H3, ow3, b3p, s3);

    finalize_kernel<<<NTOK / 4, 256, 0, stream>>>(target,
        H0, hw, hbp, sH, H1, ow1, b1p, s1, H2, ow2, b2p, s2, H3, ow3, b3p, s3,
        (float*)d_out);
}

// Round 3
// 230.656 us; speedup vs baseline: 1.2004x; 1.1012x over previous
//
#include <hip/hip_runtime.h>

typedef short s16x8 __attribute__((ext_vector_type(8)));
typedef unsigned short u16x8 __attribute__((ext_vector_type(8)));
typedef float f32x4 __attribute__((ext_vector_type(4)));
typedef unsigned short ushort;

// ---------------- problem constants ----------------
#define NTOK 1024
#define DHID 512

#define VH   20003
#define KH   512
#define NCH_H 80
#define TPC_H 16
#define VH_PAD 20480

#define V1   20000
#define K1   128
#define NCH_1 80
#define TPC_1 16
#define V1_PAD 20480

#define V2   160000
#define K2   32
#define NCH_2 128
#define TPC_2 80
#define V2_PAD 163840

#define V3   67735
#define K3   32
#define NCH_3 67
#define TPC_3 64
#define V3_PAD 68608

#define PAD_BIAS (-1e30f)
#define LOG2E 1.4426950408889634f
#define LN2F  0.6931471805599453f

// ---------------- ws layout (bytes) ----------------
#define OFF_HW   0UL
#define OFF_W1   (OFF_HW  + (unsigned long)VH_PAD*KH*2)
#define OFF_W2   (OFF_W1  + (unsigned long)V1_PAD*K1*2)
#define OFF_W3   (OFF_W2  + (unsigned long)V2_PAD*K2*2)
#define OFF_HID  (OFF_W3  + (unsigned long)V3_PAD*K3*2)
#define OFF_PT0  (OFF_HID + (unsigned long)NTOK*DHID*2)
#define OFF_PT1  (OFF_PT0 + (unsigned long)512*DHID*2)
#define OFF_PT2  (OFF_PT1 + (unsigned long)128*DHID*2)
#define OFF_PT3  (OFF_PT2 + (unsigned long)32*DHID*2)
#define OFF_H0   (OFF_PT3 + (unsigned long)32*DHID*2)
#define OFF_H1   (OFF_H0  + (unsigned long)NTOK*512*2)
#define OFF_H2   (OFF_H1  + (unsigned long)NTOK*128*2)
#define OFF_H3   (OFF_H2  + (unsigned long)NTOK*32*2)
#define OFF_HB   (OFF_H3  + (unsigned long)NTOK*32*2)
#define OFF_B1   (OFF_HB  + (unsigned long)VH_PAD*4)
#define OFF_B2   (OFF_B1  + (unsigned long)V1_PAD*4)
#define OFF_B3   (OFF_B2  + (unsigned long)V2_PAD*4)
#define OFF_SH   (OFF_B3  + (unsigned long)V3_PAD*4)
#define OFF_S1   (OFF_SH  + (unsigned long)NTOK*NCH_H*4)
#define OFF_S2   (OFF_S1  + (unsigned long)NTOK*NCH_1*4)
#define OFF_S3   (OFF_S2  + (unsigned long)NTOK*NCH_2*4)

// ---------------- helpers ----------------
__device__ __forceinline__ ushort f2bf(float f) {
    union { float f; unsigned u; } x; x.f = f;
    unsigned r = x.u + 0x7fffu + ((x.u >> 16) & 1u);
    return (ushort)(r >> 16);
}
__device__ __forceinline__ float bf2f(ushort h) {
    union { unsigned u; float f; } x; x.u = ((unsigned)h) << 16;
    return x.f;
}
__device__ __forceinline__ f32x4 mfma_bf16(s16x8 a, s16x8 b, f32x4 c) {
    return __builtin_amdgcn_mfma_f32_16x16x32_bf16(a, b, c, 0, 0, 0);
}
__device__ __forceinline__ void ld8(const float* p, float* v) {
    float4 a = *(const float4*)p, b = *(const float4*)(p + 4);
    v[0]=a.x; v[1]=a.y; v[2]=a.z; v[3]=a.w; v[4]=b.x; v[5]=b.y; v[6]=b.z; v[7]=b.w;
}
__device__ __forceinline__ void gld_lds16(const ushort* g, ushort* l) {
    __builtin_amdgcn_global_load_lds(
        (const __attribute__((address_space(1))) unsigned int*)g,
        (__attribute__((address_space(3))) unsigned int*)l, 16, 0, 0);
}

// ---------------- prep: wave-per-512-element-block swizzle ----------------
// W arrays (hw/ow1/ow2/ow3) are pre-scaled by LOG2E so the fused kernel can use
// exp2 directly; finalize multiplies gathered logits by LN2.
#define WB_HW  20480L
#define WB_W1  5120L
#define WB_W2  10240L
#define WB_W3  4288L
#define WB_HID 1024L
#define WB_PT0 512L
#define WB_PT1 128L
#define WB_PT2 32L
#define WB_PT3 32L
#define WB_TOTAL (WB_HW+WB_W1+WB_W2+WB_W3+WB_HID+WB_PT0+WB_PT1+WB_PT2+WB_PT3)

__global__ __launch_bounds__(256) void prep_wswz(
    const float* __restrict__ hidden,
    const float* __restrict__ W0, const float* __restrict__ cw,
    const float* __restrict__ W1, const float* __restrict__ W2, const float* __restrict__ W3,
    const float* __restrict__ p0, const float* __restrict__ p1,
    const float* __restrict__ p2, const float* __restrict__ p3,
    ushort* __restrict__ hw, ushort* __restrict__ ow1,
    ushort* __restrict__ ow2, ushort* __restrict__ ow3,
    ushort* __restrict__ hid,
    ushort* __restrict__ pT0, ushort* __restrict__ pT1,
    ushort* __restrict__ pT2, ushort* __restrict__ pT3)
{
    int lane = threadIdx.x & 63;
    int r = lane & 15, quad = lane >> 4;
    long wb0 = (long)blockIdx.x * 4 + (threadIdx.x >> 6);
    long nw = (long)gridDim.x * 4;
    for (long wb = wb0; wb < WB_TOTAL; wb += nw) {
        long b = wb;
        float vals[8];
        #pragma unroll
        for (int j = 0; j < 8; ++j) vals[j] = 0.f;
        float scale = LOG2E;
        ushort* dst;
        if (b < WB_HW) {
            long tile = b >> 4, ks = b & 15;
            long v = tile * 16 + r, k = ks * 32 + quad * 8;
            if (v < 20000)      ld8(W0 + v * 512 + k, vals);
            else if (v < VH)    ld8(cw + (v - 20000) * 512 + k, vals);
            dst = hw + b * 512 + (long)lane * 8;
        } else if ((b -= WB_HW) < WB_W1) {
            long tile = b >> 2, ks = b & 3;
            long v = tile * 16 + r, k = ks * 32 + quad * 8;
            if (v < V1) ld8(W1 + v * 128 + k, vals);
            dst = ow1 + b * 512 + (long)lane * 8;
        } else if ((b -= WB_W1) < WB_W2) {
            long v = b * 16 + r;
            if (v < V2) ld8(W2 + v * 32 + quad * 8, vals);
            dst = ow2 + b * 512 + (long)lane * 8;
        } else if ((b -= WB_W2) < WB_W3) {
            long v = b * 16 + r;
            if (v < V3 && quad == 0) ld8(W3 + v * 8, vals);
            dst = ow3 + b * 512 + (long)lane * 8;
        } else if ((b -= WB_W3) < WB_HID) {
            scale = 1.f;
            long tile = b >> 4, ks = b & 15;
            long v = tile * 16 + r, k = ks * 32 + quad * 8;
            ld8(hidden + v * 512 + k, vals);
            dst = hid + b * 512 + (long)lane * 8;
        } else if ((b -= WB_HID) < WB_PT0) {
            scale = 1.f;
            long tile = b >> 4, ks = b & 15;
            long c = tile * 16 + r, k = ks * 32 + quad * 8;
            #pragma unroll
            for (int j = 0; j < 8; ++j) vals[j] = p0[(k + j) * 512 + c];
            dst = pT0 + b * 512 + (long)lane * 8;
        } else if ((b -= WB_PT0) < WB_PT1) {
            scale = 1.f;
            long tile = b >> 4, ks = b & 15;
            long c = tile * 16 + r, k = ks * 32 + quad * 8;
            #pragma unroll
            for (int j = 0; j < 8; ++j) vals[j] = p1[(k + j) * 128 + c];
            dst = pT1 + b * 512 + (long)lane * 8;
        } else if ((b -= WB_PT1) < WB_PT2) {
            scale = 1.f;
            long tile = b >> 4, ks = b & 15;
            long c = tile * 16 + r, k = ks * 32 + quad * 8;
            #pragma unroll
            for (int j = 0; j < 8; ++j) vals[j] = p2[(k + j) * 32 + c];
            dst = pT2 + b * 512 + (long)lane * 8;
        } else {
            scale = 1.f;
            b -= WB_PT2;
            long tile = b >> 4, ks = b & 15;
            long c = tile * 16 + r, k = ks * 32 + quad * 8;
            if (c < 8) {
                #pragma unroll
                for (int j = 0; j < 8; ++j) vals[j] = p3[(k + j) * 8 + c];
            }
            dst = pT3 + b * 512 + (long)lane * 8;
        }
        u16x8 o;
        #pragma unroll
        for (int j = 0; j < 8; ++j) o[j] = f2bf(vals[j] * scale);
        *(u16x8*)dst = o;
    }
}

// ---------------- prep: padded biases (pre-scaled by LOG2E) ----------------
#define E_HB  ((long)VH_PAD)
#define E_B1  ((long)V1_PAD)
#define E_B2  ((long)V2_PAD)
#define E_B3  ((long)V3_PAD)
#define E_BIAS (E_HB+E_B1+E_B2+E_B3)

__global__ __launch_bounds__(256) void prep_bias(
    const float* __restrict__ b0, const float* __restrict__ b1,
    const float* __restrict__ b2, const float* __restrict__ b3,
    const float* __restrict__ cb,
    float* __restrict__ hbp, float* __restrict__ ob1,
    float* __restrict__ ob2, float* __restrict__ ob3)
{
    long stride = (long)gridDim.x * blockDim.x;
    for (long i = (long)blockIdx.x * blockDim.x + threadIdx.x; i < E_BIAS; i += stride) {
        long j = i;
        if (j < E_HB) {
            hbp[j] = ((j < 20000) ? b0[j] : (j < VH) ? cb[j - 20000] : PAD_BIAS) * LOG2E;
        } else if ((j -= E_HB) < E_B1) {
            ob1[j] = ((j < V1) ? b1[j] : PAD_BIAS) * LOG2E;
        } else if ((j -= E_B1) < E_B2) {
            ob2[j] = ((j < V2) ? b2[j] : PAD_BIAS) * LOG2E;
        } else { j -= E_B2;
            ob3[j] = ((j < V3) ? b3[j] : PAD_BIAS) * LOG2E;
        }
    }
}

// ---------------- gemm_h body + merged launch ----------------
__device__ __forceinline__ void gemm_body(
    const ushort* __restrict__ A, const ushort* __restrict__ Bt,
    ushort* __restrict__ Hout, int dpad, int c_tile)
{
    int wave = threadIdx.x >> 6, lane = threadIdx.x & 63;
    int quad = lane >> 4, colid = lane & 15;
    int m_tile = blockIdx.x * 4 + wave;
    const ushort* Ab = A + ((long)m_tile * 16) * 512 + lane * 8;
    const ushort* Bb = Bt + ((long)c_tile * 16) * 512 + lane * 8;
    f32x4 acc = {0.f, 0.f, 0.f, 0.f};
    #pragma unroll
    for (int ks = 0; ks < 16; ++ks) {
        s16x8 a = *(const s16x8*)(Ab + ks * 512);
        s16x8 b = *(const s16x8*)(Bb + ks * 512);
        acc = mfma_bf16(a, b, acc);
    }
    int KBo = dpad >> 5;
    int col = c_tile * 16 + colid;
    int ks_o = col >> 5, q_o = (col >> 3) & 3, j_o = col & 7;
    #pragma unroll
    for (int r = 0; r < 4; ++r) {
        int rm = quad * 4 + r;
        Hout[((long)m_tile * KBo + ks_o) * 512 + (q_o * 16 + rm) * 8 + j_o] = f2bf(acc[r]);
    }
}

__global__ __launch_bounds__(256) void gemm_all(
    const ushort* __restrict__ hid,
    const ushort* __restrict__ pT0, const ushort* __restrict__ pT1,
    const ushort* __restrict__ pT2, const ushort* __restrict__ pT3,
    ushort* __restrict__ H0, ushort* __restrict__ H1,
    ushort* __restrict__ H2, ushort* __restrict__ H3)
{
    int y = blockIdx.y;
    if (y < 32)      gemm_body(hid, pT0, H0, 512, y);
    else if (y < 40) gemm_body(hid, pT1, H1, 128, y - 32);
    else if (y < 42) gemm_body(hid, pT2, H2, 32,  y - 40);
    else             gemm_body(hid, pT3, H3, 32,  y - 42);
}

// ---------------- fused GEMM + exp2-sum: MREP + 3-buffer counted-vmcnt ----------------
template<int TG>
__device__ __forceinline__ void stage_grp(const ushort* __restrict__ g,
                                          ushort* __restrict__ l,
                                          int wave, int lane)
{
    constexpr int LPW = TG / 4;
    const ushort* gp = g + ((long)wave * LPW) * 512 + lane * 8;
    ushort* lp = l + wave * LPW * 512;
    #pragma unroll
    for (int i = 0; i < LPW; ++i) gld_lds16(gp + i * 512, lp + i * 512);
}

template<int KB, int MREP, int TG>
__device__ __forceinline__ void compute_grp(const ushort* __restrict__ buf,
                                            const s16x8 (&afrag)[MREP][KB],
                                            const float* __restrict__ ldsB,
                                            int tb0, int lane, int colid,
                                            float (&s_acc)[MREP][4])
{
    constexpr int TPG = TG / KB;
    f32x4 acc0[TPG][MREP];
    f32x4 acc1[(KB > 1) ? TPG : 1][(KB > 1) ? MREP : 1];
    float bv[TPG];
    #pragma unroll
    for (int t = 0; t < TPG; ++t) bv[t] = ldsB[(tb0 + t) * 16 + colid];
    #pragma unroll
    for (int t = 0; t < TPG; ++t)
        #pragma unroll
        for (int i = 0; i < MREP; ++i) {
            acc0[t][i] = (f32x4){bv[t], bv[t], bv[t], bv[t]};  // bias folded into init
            if (KB > 1) acc1[t][i] = (f32x4){0.f, 0.f, 0.f, 0.f};
        }
    #pragma unroll
    for (int b = 0; b < TG; ++b) {
        s16x8 bb = *(const s16x8*)(buf + b * 512 + lane * 8);
        int t = b / KB, ks = b % KB;               // compile-time after unroll
        #pragma unroll
        for (int i = 0; i < MREP; ++i) {
            if ((KB > 1) && (ks & 1))
                acc1[t][i] = mfma_bf16(afrag[i][ks], bb, acc1[t][i]);
            else
                acc0[t][i] = mfma_bf16(afrag[i][ks], bb, acc0[t][i]);
        }
    }
    #pragma unroll
    for (int t = 0; t < TPG; ++t)
        #pragma unroll
        for (int i = 0; i < MREP; ++i)
            #pragma unroll
            for (int r = 0; r < 4; ++r) {
                float v = acc0[t][i][r];
                if (KB > 1) v += acc1[t][i][r];
                s_acc[i][r] += __builtin_amdgcn_exp2f(v);
            }
}

template<int KB, int MREP, int TG>
__device__ __forceinline__ void fused_path(
    const ushort* __restrict__ A, const ushort* __restrict__ W,
    const float* __restrict__ bias, float* __restrict__ part_s,
    int tpc, int n_chunks, int chunk, int mblk,
    ushort* __restrict__ ldsW, float* __restrict__ ldsB)
{
    constexpr int TPG = TG / KB;
    constexpr int LPW = TG / 4;
    constexpr int BUFE = TG * 512;
    int wave = threadIdx.x >> 6, lane = threadIdx.x & 63;
    int quad = lane >> 4, colid = lane & 15;
    int mt0 = mblk * (4 * MREP) + wave * MREP;
    long t0 = (long)chunk * tpc;
    const ushort* Wc = W + t0 * KB * 512;
    const int ng = (tpc * KB) / TG;

    // A fragments for MREP m-tiles, pinned in VGPRs
    s16x8 afrag[MREP][KB];
    #pragma unroll
    for (int i = 0; i < MREP; ++i) {
        const ushort* Ab = A + ((long)(mt0 + i) * KB) * 512 + lane * 8;
        #pragma unroll
        for (int ks = 0; ks < KB; ++ks) afrag[i][ks] = *(const s16x8*)(Ab + ks * 512);
    }
    // bias -> LDS (main loop then has zero stray VMEM)
    int nb = tpc * 16;
    for (int i = threadIdx.x; i < nb; i += 256) ldsB[i] = bias[t0 * 16 + i];
    __syncthreads();
    #pragma unroll
    for (int i = 0; i < MREP; ++i)
        #pragma unroll
        for (int ks = 0; ks < KB; ++ks) asm volatile("" : "+v"(afrag[i][ks]));

    float s_acc[MREP][4];
    #pragma unroll
    for (int i = 0; i < MREP; ++i)
        #pragma unroll
        for (int r = 0; r < 4; ++r) s_acc[i][r] = 0.f;

    stage_grp<TG>(Wc, ldsW, wave, lane);
    stage_grp<TG>(Wc + BUFE, ldsW + BUFE, wave, lane);

    for (int g = 0; g < ng - 1; ++g) {
        if constexpr (LPW == 1)      asm volatile("s_waitcnt vmcnt(1)" ::: "memory");
        else if constexpr (LPW == 2) asm volatile("s_waitcnt vmcnt(2)" ::: "memory");
        else                         asm volatile("s_waitcnt vmcnt(4)" ::: "memory");
        __builtin_amdgcn_s_barrier();
        if (g + 2 < ng)
            stage_grp<TG>(Wc + (long)(g + 2) * BUFE,
                          ldsW + ((g + 2) % 3) * BUFE, wave, lane);
        compute_grp<KB, MREP, TG>(ldsW + (g % 3) * BUFE, afrag, ldsB,
                                  g * TPG, lane, colid, s_acc);
        asm volatile("s_waitcnt lgkmcnt(0)" ::: "memory");
    }
    asm volatile("s_waitcnt vmcnt(0)" ::: "memory");
    __builtin_amdgcn_s_barrier();
    compute_grp<KB, MREP, TG>(ldsW + ((ng - 1) % 3) * BUFE, afrag, ldsB,
                              (ng - 1) * TPG, lane, colid, s_acc);

    #pragma unroll
    for (int i = 0; i < MREP; ++i)
        #pragma unroll
        for (int r = 0; r < 4; ++r) {
            float v = s_acc[i][r];
            v += __shfl_xor(v, 1);
            v += __shfl_xor(v, 2);
            v += __shfl_xor(v, 4);
            v += __shfl_xor(v, 8);
            s_acc[i][r] = v;
        }
    if (colid == 0) {
        #pragma unroll
        for (int i = 0; i < MREP; ++i)
            #pragma unroll
            for (int r = 0; r < 4; ++r) {
                int m = (mt0 + i) * 16 + quad * 4 + r;
                part_s[(long)m * n_chunks + chunk] = s_acc[i][r];
            }
    }
}

// Block counts: head 80*8=640, tail1 80*4=320, tail2 128*4=512, tail3 67*4=268.
// Total 1740. Bijective XCD-chunked swizzle: q=217, r=4.
__global__ __launch_bounds__(256, 3) void fused_all(
    const ushort* __restrict__ H0, const ushort* __restrict__ hw,
    const float* __restrict__ hbp, float* __restrict__ sH,
    const ushort* __restrict__ H1, const ushort* __restrict__ w1,
    const float* __restrict__ b1p, float* __restrict__ s1,
    const ushort* __restrict__ H2, const ushort* __restrict__ w2,
    const float* __restrict__ b2p, float* __restrict__ s2,
    const ushort* __restrict__ H3, const ushort* __restrict__ w3,
    const float* __restrict__ b3p, float* __restrict__ s3)
{
    __shared__ __align__(16) ushort ldsW[3 * 16 * 512];
    __shared__ float ldsB[1280];
    int bid = blockIdx.x;
    int k = bid & 7, j = bid >> 3;
    int L = k * 217 + (k < 4 ? k : 4) + j;
    if (L < 640) {
        fused_path<16, 2, 16>(H0, hw, hbp, sH, TPC_H, NCH_H, L >> 3, L & 7, ldsW, ldsB);
    } else if (L < 960) {
        int t = L - 640;
        fused_path<4, 4, 8>(H1, w1, b1p, s1, TPC_1, NCH_1, t >> 2, t & 3, ldsW, ldsB);
    } else if (L < 1472) {
        int t = L - 960;
        fused_path<1, 4, 4>(H2, w2, b2p, s2, TPC_2, NCH_2, t >> 2, t & 3, ldsW, ldsB);
    } else {
        int t = L - 1472;
        fused_path<1, 4, 4>(H3, w3, b3p, s3, TPC_3, NCH_3, t >> 2, t & 3, ldsW, ldsB);
    }
}

// ---------------- finalize ----------------
__device__ __forceinline__ float swz_dot(const ushort* __restrict__ H, int m,
                                         const ushort* __restrict__ Wm, long vrow,
                                         int K, int lane)
{
    float d = 0.f;
    if (lane * 8 < K) {
        int ks = lane >> 2, q = lane & 3;
        int KB = K >> 5;
        const ushort* hp = H + ((long)(m >> 4) * KB + ks) * 512 + (q * 16 + (m & 15)) * 8;
        const ushort* wp = Wm + ((vrow >> 4) * KB + ks) * 512 + (q * 16 + (int)(vrow & 15)) * 8;
        #pragma unroll
        for (int j = 0; j < 8; ++j) d += bf2f(hp[j]) * bf2f(wp[j]);
    }
    d += __shfl_xor(d, 1);  d += __shfl_xor(d, 2);  d += __shfl_xor(d, 4);
    d += __shfl_xor(d, 8);  d += __shfl_xor(d, 16); d += __shfl_xor(d, 32);
    return d;
}

__global__ __launch_bounds__(256) void finalize_kernel(
    const int* __restrict__ target,
    const ushort* __restrict__ H0, const ushort* __restrict__ hw,
    const float* __restrict__ hbp, const float* __restrict__ sH,
    const ushort* __restrict__ H1, const ushort* __restrict__ w1,
    const float* __restrict__ b1p, const float* __restrict__ s1,
    const ushort* __restrict__ H2, const ushort* __restrict__ w2,
    const float* __restrict__ b2p, const float* __restrict__ s2,
    const ushort* __restrict__ H3, const ushort* __restrict__ w3,
    const float* __restrict__ b3p, const float* __restrict__ s3,
    float* __restrict__ out)
{
    int wave = threadIdx.x >> 6, lane = threadIdx.x & 63;
    int m = blockIdx.x * 4 + wave;
    int t = target[m];
    int cid = (t >= 20000) + (t >= 40000) + (t >= 200000);

    float s = 0.f;
    for (int i = lane; i < NCH_H; i += 64) s += sH[(long)m * NCH_H + i];
    s += __shfl_xor(s, 1);  s += __shfl_xor(s, 2);  s += __shfl_xor(s, 4);
    s += __shfl_xor(s, 8);  s += __shfl_xor(s, 16); s += __shfl_xor(s, 32);
    float lse_h = __logf(s);

    int hc = (cid == 0) ? t : (20003 - cid);
    float d = swz_dot(H0, m, hw, hc, 512, lane);          // scaled by LOG2E
    float nll = lse_h - (d + hbp[hc]) * LN2F;

    if (cid > 0) {
        const ushort *Hi, *Wi; const float *bi, *si; int K, nc, l;
        if (cid == 1)      { Hi = H1; Wi = w1; bi = b1p; si = s1; K = 128; nc = NCH_1; l = 20000; }
        else if (cid == 2) { Hi = H2; Wi = w2; bi = b2p; si = s2; K = 32;  nc = NCH_2; l = 40000; }
        else               { Hi = H3; Wi = w3; bi = b3p; si = s3; K = 32;  nc = NCH_3; l = 200000; }
        int rel = t - l;
        float ts = 0.f;
        for (int i = lane; i < nc; i += 64) ts += si[(long)m * nc + i];
        ts += __shfl_xor(ts, 1);  ts += __shfl_xor(ts, 2);  ts += __shfl_xor(ts, 4);
        ts += __shfl_xor(ts, 8);  ts += __shfl_xor(ts, 16); ts += __shfl_xor(ts, 32);
        float lse_t = __logf(ts);
        float dt = swz_dot(Hi, m, Wi, rel, K, lane);      // scaled by LOG2E
        nll += lse_t - (dt + bi[rel]) * LN2F;
    }
    if (lane == 0) out[m] = nll;
}

// ---------------- host ----------------
extern "C" void kernel_launch(void* const* d_in, const int* in_sizes, int n_in,
                              void* d_out, int out_size, void* d_ws, size_t ws_size,
                              hipStream_t stream) {
    const float* hidden = (const float*)d_in[0];
    const int*   target = (const int*)d_in[1];
    const float* W0 = (const float*)d_in[2];
    const float* b0 = (const float*)d_in[3];
    const float* p0 = (const float*)d_in[4];
    const float* W1 = (const float*)d_in[5];
    const float* b1 = (const float*)d_in[6];
    const float* p1 = (const float*)d_in[7];
    const float* W2 = (const float*)d_in[8];
    const float* b2 = (const float*)d_in[9];
    const float* p2 = (const float*)d_in[10];
    const float* W3 = (const float*)d_in[11];
    const float* b3 = (const float*)d_in[12];
    const float* p3 = (const float*)d_in[13];
    const float* cw = (const float*)d_in[14];
    const float* cb = (const float*)d_in[15];

    char* ws = (char*)d_ws;
    ushort* hw  = (ushort*)(ws + OFF_HW);
    ushort* ow1 = (ushort*)(ws + OFF_W1);
    ushort* ow2 = (ushort*)(ws + OFF_W2);
    ushort* ow3 = (ushort*)(ws + OFF_W3);
    ushort* hid = (ushort*)(ws + OFF_HID);
    ushort* pT0 = (ushort*)(ws + OFF_PT0);
    ushort* pT1 = (ushort*)(ws + OFF_PT1);
    ushort* pT2 = (ushort*)(ws + OFF_PT2);
    ushort* pT3 = (ushort*)(ws + OFF_PT3);
    ushort* H0  = (ushort*)(ws + OFF_H0);
    ushort* H1  = (ushort*)(ws + OFF_H1);
    ushort* H2  = (ushort*)(ws + OFF_H2);
    ushort* H3  = (ushort*)(ws + OFF_H3);
    float* hbp = (float*)(ws + OFF_HB);
    float* b1p = (float*)(ws + OFF_B1);
    float* b2p = (float*)(ws + OFF_B2);
    float* b3p = (float*)(ws + OFF_B3);
    float* sH  = (float*)(ws + OFF_SH);
    float* s1  = (float*)(ws + OFF_S1);
    float* s2  = (float*)(ws + OFF_S2);
    float* s3  = (float*)(ws + OFF_S3);

    prep_wswz<<<10464, 256, 0, stream>>>(hidden, W0, cw, W1, W2, W3,
                                         p0, p1, p2, p3,
                                         hw, ow1, ow2, ow3, hid, pT0, pT1, pT2, pT3);
    prep_bias<<<1072, 256, 0, stream>>>(b0, b1, b2, b3, cb, hbp, b1p, b2p, b3p);

    gemm_all<<<dim3(NTOK / 64, 44), 256, 0, stream>>>(hid, pT0, pT1, pT2, pT3,
                                                      H0, H1, H2, H3);

    fused_all<<<1740, 256, 0, stream>>>(H0, hw, hbp, sH,
                                        H1, ow1, b1p, s1,
                                        H2, ow2, b2p, s2,
                                        H3, ow3, b3p, s3);

    finalize_kernel<<<NTOK / 4, 256, 0, stream>>>(target,
        H0, hw, hbp, sH, H1, ow1, b1p, s1, H2, ow2, b2p, s2, H3, ow3, b3p, s3,
        (float*)d_out);
}